// Round 10
// baseline (56.648 us; speedup 1.0000x reference)
//
#include <hip/hip_runtime.h>

// Depth-4 path signature, C=10, L=64, B=2048 — MFMA formulation (R10).
// Closed form (validated R8/R9, absmax 5.25 vs thr 12.16):
//   P_t = exclusive prefix of dx;  R_t[l] = S1[l] - P_{t+1}[l]
//   per (i,j): s2 sequential; v2_t, u2_t level-2 Horner scalars
//   S4[ij,kl] = sum_t v2_t*(dx_t[k]*R_t[l]) + sum_t u2_t*(dx_t[k]*dx_t[l]/2)
//   S3[ij,k]  = sum_t v2_t*dx_t[k]
// R10 vs R9: two K=64 GEMM passes with acc carried in registers:
//   pass 0: A=V2(100x64), B=[dx ox R | dx](110x64)
//   pass 1: A=U2,         B=[dx ox dx /2 | 0]
// This allows row stride KS=64 shorts = 128B == 0 mod 32 banks, so the XOR
// granule swizzle  off = row*64 + ((k>>3 ^ row&7)<<3 | k&7)  is an exact
// bank-group permutation for BOTH column-writes and k-reads (R9's 272B
// stride added a row term mod 8 -> residual 8M conflicts). Also halves
// LDS to 33.5 KB -> 3-4 blocks/CU (was 2).

typedef short short8 __attribute__((ext_vector_type(8)));
typedef float f32x4 __attribute__((ext_vector_type(4)));
typedef unsigned int uint4v __attribute__((ext_vector_type(4)));

constexpr int C = 10, L = 64, T = 63;          // T = L-1 steps
constexpr int OUTSZ = 10 + 100 + 1000 + 10000; // 11110
constexpr int DXP = 13;                        // dx/P row stride (fp32 words)
constexpr int KS = 64;                         // A/B row stride in shorts (128B)

__device__ __forceinline__ unsigned short f2bf(float f) {  // RNE f32->bf16
  unsigned u = __float_as_uint(f);
  return (unsigned short)((u + 0x7FFFu + ((u >> 16) & 1u)) >> 16);
}
__device__ __forceinline__ int swz(int row, int k) {  // short idx, 16B-granule XOR
  return row * KS + ((((k >> 3) ^ (row & 7)) << 3) | (k & 7));
}

__global__ __launch_bounds__(256, 3) void sig4_kernel(
    const float* __restrict__ x, float* __restrict__ out)
{
  __shared__ __align__(16) unsigned short Ab[100 * KS];  // 12.8 KB
  __shared__ __align__(16) unsigned short Bb[110 * KS];  // 14.1 KB
  __shared__ float dxs[T * DXP];                         // 3.3 KB
  __shared__ float Ps[64 * DXP];                         // 3.3 KB

  const int t = threadIdx.x;
  const float* __restrict__ xb = x + (size_t)blockIdx.x * (C * L);
  float* __restrict__ ob = out + (size_t)blockIdx.x * OUTSZ;

  // ---- phase A: path -> dx, exclusive prefix P (shuffle scan) ----
  float* pl = (float*)Bb;  // alias: Bb first written after last pl read
  for (int i = t; i < C * L; i += 256) pl[i] = xb[i];
  __syncthreads();
  for (int i = t; i < T * C; i += 256) {
    int s = i / C, c = i - s * C;
    dxs[s * DXP + c] = pl[c * L + s + 1] - pl[c * L + s];
  }
  __syncthreads();
  {
    int w = t >> 6, lane = t & 63;
    for (int c = w; c < C; c += 4) {
      float v = (lane > 0) ? dxs[(lane - 1) * DXP + c] : 0.f;
      #pragma unroll
      for (int d = 1; d < 64; d <<= 1) {
        float y = __shfl_up(v, d);
        if (lane >= d) v += y;
      }
      Ps[lane * DXP + c] = v;   // P[t][c] = sum_{s<t} dx_s[c]; P[63] = S1
    }
  }
  __syncthreads();

  const int w = t >> 6, lane = t & 63;
  const int lm = lane & 15, lg = lane >> 4;

  f32x4 acc[2][7];
  #pragma unroll
  for (int rti = 0; rti < 2; ++rti)
    #pragma unroll
    for (int ct = 0; ct < 7; ++ct) acc[rti][ct] = f32x4{0.f, 0.f, 0.f, 0.f};

  #pragma unroll 1
  for (int pass = 0; pass < 2; ++pass) {
    // ---- build A (lanes 0..99) || B (lanes 128..255) for this pass ----
    if (t < 100) {
      const int i_ = t / 10, j_ = t - i_ * 10;
      float s2 = 0.f;
      #pragma unroll
      for (int ch = 0; ch < 8; ++ch) {   // 8 k-values per b128 write
        unsigned pk[4];
        #pragma unroll
        for (int e = 0; e < 8; ++e) {
          const int s = ch * 8 + e;
          float val = 0.f;
          if (s < T) {
            float di = dxs[s * DXP + i_];
            float dj = dxs[s * DXP + j_];
            float p  = Ps[s * DXP + i_];
            val = (pass == 0)
                ? fmaf(fmaf(di, (1.f / 3.f), p), dj * 0.5f, s2)        // v2
                : fmaf(fmaf(di, 0.25f, p), dj * (1.f / 3.f), s2);      // u2
            s2 = fmaf(fmaf(di, 0.5f, p), dj, s2);
          }
          unsigned vb = f2bf(val);
          if ((e & 1) == 0) pk[e >> 1] = vb; else pk[e >> 1] |= vb << 16;
        }
        *(uint4v*)&Ab[swz(t, ch * 8)] = uint4v{pk[0], pk[1], pk[2], pk[3]};
      }
      if (pass == 0) {
        ob[10 + t] = s2;                            // S2 (exact fp32)
        if (j_ == 0) ob[i_] = Ps[63 * DXP + i_];    // S1
      }
    } else if (t >= 128) {
      const int q = t - 128;
      for (int task = q; task < 110 * 8; task += 128) {
        const int col = task >> 3, ch = task & 7;
        unsigned pk[4];
        if (col < 100) {
          const int k2 = col / 10, l2 = col - k2 * 10;
          const float S1l = Ps[63 * DXP + l2];
          #pragma unroll
          for (int e = 0; e < 8; ++e) {
            const int kk = ch * 8 + e;
            float bval = 0.f;
            if (kk < T) {
              float d = dxs[kk * DXP + k2];
              if (pass == 0) bval = d * (S1l - Ps[(kk + 1) * DXP + l2]);
              else           bval = d * dxs[kk * DXP + l2] * 0.5f;
            }
            unsigned vb = f2bf(bval);
            if ((e & 1) == 0) pk[e >> 1] = vb; else pk[e >> 1] |= vb << 16;
          }
        } else {
          const int c2 = col - 100;
          #pragma unroll
          for (int e = 0; e < 8; ++e) {
            const int kk = ch * 8 + e;
            float bval = (pass == 0 && kk < T) ? dxs[kk * DXP + c2] : 0.f;
            unsigned vb = f2bf(bval);
            if ((e & 1) == 0) pk[e >> 1] = vb; else pk[e >> 1] |= vb << 16;
          }
        }
        *(uint4v*)&Bb[swz(col, ch * 8)] = uint4v{pk[0], pk[1], pk[2], pk[3]};
      }
    }
    __syncthreads();

    // ---- GEMM accumulate: C(100x110) += A(100x64) x B(110x64)^T_k ----
    #pragma unroll
    for (int rti = 0; rti < 2; ++rti) {
      const int rt = w + rti * 4;
      if (rt < 7) {
        const int arow = rt * 16 + lm;
        short8 a0 = (arow < 100) ? *(const short8*)&Ab[swz(arow, lg * 8)]
                                 : short8{0, 0, 0, 0, 0, 0, 0, 0};
        short8 a1 = (arow < 100) ? *(const short8*)&Ab[swz(arow, 32 + lg * 8)]
                                 : short8{0, 0, 0, 0, 0, 0, 0, 0};
        #pragma unroll
        for (int ct = 0; ct < 7; ++ct) {
          const int bcol = ct * 16 + lm;
          short8 b0 = (bcol < 110) ? *(const short8*)&Bb[swz(bcol, lg * 8)]
                                   : short8{0, 0, 0, 0, 0, 0, 0, 0};
          short8 b1 = (bcol < 110) ? *(const short8*)&Bb[swz(bcol, 32 + lg * 8)]
                                   : short8{0, 0, 0, 0, 0, 0, 0, 0};
          acc[rti][ct] = __builtin_amdgcn_mfma_f32_16x16x32_bf16(
              a0, b0, acc[rti][ct], 0, 0, 0);
          acc[rti][ct] = __builtin_amdgcn_mfma_f32_16x16x32_bf16(
              a1, b1, acc[rti][ct], 0, 0, 0);
        }
      }
    }
    if (pass == 0) __syncthreads();   // protect Ab/Bb before pass-1 rebuild
  }

  // ---- epilogue: write C from registers ----
  #pragma unroll
  for (int rti = 0; rti < 2; ++rti) {
    const int rt = w + rti * 4;
    if (rt < 7) {
      const int rbase = rt * 16 + lg * 4;
      #pragma unroll
      for (int ct = 0; ct < 7; ++ct) {
        const int bcol = ct * 16 + lm;
        #pragma unroll
        for (int r = 0; r < 4; ++r) {
          const int row = rbase + r;
          if (row < 100) {
            if (bcol < 100)      ob[1110 + row * 100 + bcol] = acc[rti][ct][r];
            else if (bcol < 110) ob[110 + row * 10 + (bcol - 100)] = acc[rti][ct][r];
          }
        }
      }
    }
  }
}

extern "C" void kernel_launch(void* const* d_in, const int* in_sizes, int n_in,
                              void* d_out, int out_size, void* d_ws, size_t ws_size,
                              hipStream_t stream) {
  const float* x = (const float*)d_in[0];
  float* out = (float*)d_out;
  const int batch = in_sizes[0] / (C * L);   // 2048
  sig4_kernel<<<dim3(batch), dim3(256), 0, stream>>>(x, out);
}

// Round 11
// 46.040 us; speedup vs baseline: 1.2304x; 1.2304x over previous
//
#include <hip/hip_runtime.h>

// Depth-4 path signature, C=10, L=64, B=2048 — MFMA formulation (R11).
// Closed form (validated R8-R10, absmax 5.25 vs thr 12.16):
//   P_t = exclusive prefix of dx;  R_t[l] = S1[l] - P_{t+1}[l]
//   per (i,j): s2 sequential; u2_t, v2_t level-2 Horner scalars
//   S4[ij,kl] = sum_t v2_t*(dx_t[k]*R_t[l]) + sum_t u2_t*(dx_t[k]*dx_t[l]/2)
//   S3[ij,k]  = sum_t v2_t*dx_t[k]
// One K=128 GEMM per elem: A(100x128)=[V2|U2], B(110x128)=[dx ox R | dx ; dx ox dx/2 | 0],
// C(100x110): cols 0..99 = S4, 100..109 = S3.
// R11 vs R9 (best measured, 49.9us): ONE change — KS 136 -> 128 shorts.
// Row stride 256B == 0 mod 128B, so bank-group = (k>>3)^(row&7) exactly
// permutes groups for BOTH column-writes and k-reads (R9's 272B stride
// added a row term mod 8 -> 8M residual conflict cycles ~= 13us/CU).
// R10 proved the stride==0-mod-128B fix (2.8M) but paid a double build;
// single-pass keeps build cost at R9's level.

typedef short short8 __attribute__((ext_vector_type(8)));
typedef float f32x4 __attribute__((ext_vector_type(4)));
typedef unsigned int uint4v __attribute__((ext_vector_type(4)));

constexpr int C = 10, L = 64, T = 63;          // T = L-1 steps
constexpr int OUTSZ = 10 + 100 + 1000 + 10000; // 11110
constexpr int DXP = 13;                        // dx/P row stride (fp32 words)
constexpr int KS = 128;                        // A/B row stride in shorts (256B)

__device__ __forceinline__ unsigned short f2bf(float f) {  // RNE f32->bf16
  unsigned u = __float_as_uint(f);
  return (unsigned short)((u + 0x7FFFu + ((u >> 16) & 1u)) >> 16);
}
__device__ __forceinline__ int swz(int row, int k) {  // short idx, 16B-granule XOR
  return row * KS + ((((k >> 3) ^ (row & 7)) << 3) | (k & 7));
}

__global__ __launch_bounds__(256, 2) void sig4_kernel(
    const float* __restrict__ x, float* __restrict__ out)
{
  __shared__ __align__(16) unsigned short Ab[100 * KS];  // 25.6 KB
  __shared__ __align__(16) unsigned short Bb[110 * KS];  // 28.2 KB
  __shared__ float dxs[T * DXP];                         // 3.3 KB
  __shared__ float Ps[64 * DXP];                         // 3.3 KB

  const int t = threadIdx.x;
  const float* __restrict__ xb = x + (size_t)blockIdx.x * (C * L);
  float* __restrict__ ob = out + (size_t)blockIdx.x * OUTSZ;

  // ---- phase A: path -> dx, exclusive prefix P (shuffle scan) ----
  float* pl = (float*)Bb;  // alias: Bb first written after last pl read
  for (int i = t; i < C * L; i += 256) pl[i] = xb[i];
  __syncthreads();
  for (int i = t; i < T * C; i += 256) {
    int s = i / C, c = i - s * C;
    dxs[s * DXP + c] = pl[c * L + s + 1] - pl[c * L + s];
  }
  __syncthreads();
  {
    int w = t >> 6, lane = t & 63;
    for (int c = w; c < C; c += 4) {
      float v = (lane > 0) ? dxs[(lane - 1) * DXP + c] : 0.f;
      #pragma unroll
      for (int d = 1; d < 64; d <<= 1) {
        float y = __shfl_up(v, d);
        if (lane >= d) v += y;
      }
      Ps[lane * DXP + c] = v;   // P[t][c] = sum_{s<t} dx_s[c]; P[63] = S1
    }
  }
  __syncthreads();

  // ---- phase B: A-build (lanes 0..99) || B-build (lanes 128..255) ----
  if (t < 100) {
    const int i_ = t / 10, j_ = t - i_ * 10;
    float s2 = 0.f;
    #pragma unroll
    for (int ch = 0; ch < 8; ++ch) {     // 8 steps per chunk -> 2 b128 writes
      unsigned vpk[4], upk[4];
      #pragma unroll
      for (int e = 0; e < 8; ++e) {
        const int s = ch * 8 + e;
        float u2 = 0.f, v2 = 0.f;
        if (s < T) {
          float di = dxs[s * DXP + i_];
          float dj = dxs[s * DXP + j_];
          float p  = Ps[s * DXP + i_];
          u2 = fmaf(fmaf(di, 0.25f, p), dj * (1.f / 3.f), s2);
          v2 = fmaf(fmaf(di, (1.f / 3.f), p), dj * 0.5f, s2);
          s2 = fmaf(fmaf(di, 0.5f, p), dj, s2);
        }
        unsigned vb = f2bf(v2), ub = f2bf(u2);
        if ((e & 1) == 0) { vpk[e >> 1] = vb; upk[e >> 1] = ub; }
        else             { vpk[e >> 1] |= vb << 16; upk[e >> 1] |= ub << 16; }
      }
      *(uint4v*)&Ab[swz(t, ch * 8)]      = uint4v{vpk[0], vpk[1], vpk[2], vpk[3]};
      *(uint4v*)&Ab[swz(t, 64 + ch * 8)] = uint4v{upk[0], upk[1], upk[2], upk[3]};
    }
    ob[10 + t] = s2;                            // S2 (exact fp32)
    if (j_ == 0) ob[i_] = Ps[63 * DXP + i_];    // S1
  } else if (t >= 128) {
    const int q = t - 128;
    for (int task = q; task < 110 * 8; task += 128) {  // (col, k-chunk) tasks
      const int col = task >> 3, ch = task & 7;
      unsigned b1pk[4], b2pk[4];
      if (col < 100) {
        const int k2 = col / 10, l2 = col - k2 * 10;
        const float S1l = Ps[63 * DXP + l2];
        #pragma unroll
        for (int e = 0; e < 8; ++e) {
          const int kk = ch * 8 + e;
          float b1 = 0.f, b2 = 0.f;
          if (kk < T) {
            float d  = dxs[kk * DXP + k2];
            float dl = dxs[kk * DXP + l2];
            float R  = S1l - Ps[(kk + 1) * DXP + l2];
            b1 = d * R;
            b2 = d * dl * 0.5f;
          }
          unsigned x1 = f2bf(b1), x2 = f2bf(b2);
          if ((e & 1) == 0) { b1pk[e >> 1] = x1; b2pk[e >> 1] = x2; }
          else             { b1pk[e >> 1] |= x1 << 16; b2pk[e >> 1] |= x2 << 16; }
        }
      } else {
        const int c2 = col - 100;
        #pragma unroll
        for (int e = 0; e < 8; ++e) {
          const int kk = ch * 8 + e;
          float b1 = (kk < T) ? dxs[kk * DXP + c2] : 0.f;
          unsigned x1 = f2bf(b1);
          if ((e & 1) == 0) { b1pk[e >> 1] = x1; b2pk[e >> 1] = 0u; }
          else             { b1pk[e >> 1] |= x1 << 16; }
        }
      }
      *(uint4v*)&Bb[swz(col, ch * 8)]      = uint4v{b1pk[0], b1pk[1], b1pk[2], b1pk[3]};
      *(uint4v*)&Bb[swz(col, 64 + ch * 8)] = uint4v{b2pk[0], b2pk[1], b2pk[2], b2pk[3]};
    }
  }
  __syncthreads();

  // ---- phase C: per-block GEMM C(100x110) = A(100x128) x B(128x110) ----
  const int w = t >> 6, lane = t & 63;
  const int lm = lane & 15, lg = lane >> 4;
  for (int rt = w; rt < 7; rt += 4) {            // waves: {0,4},{1,5},{2,6},{3}
    const int arow = rt * 16 + lm;
    short8 a[4];
    #pragma unroll
    for (int ks = 0; ks < 4; ++ks)
      a[ks] = (arow < 100) ? *(const short8*)&Ab[swz(arow, ks * 32 + lg * 8)]
                           : short8{0, 0, 0, 0, 0, 0, 0, 0};
    for (int ct = 0; ct < 7; ++ct) {
      const int bcol = ct * 16 + lm;
      f32x4 acc = {0.f, 0.f, 0.f, 0.f};
      #pragma unroll
      for (int ks = 0; ks < 4; ++ks) {
        short8 bf = (bcol < 110)
            ? *(const short8*)&Bb[swz(bcol, ks * 32 + lg * 8)]
            : short8{0, 0, 0, 0, 0, 0, 0, 0};
        acc = __builtin_amdgcn_mfma_f32_16x16x32_bf16(a[ks], bf, acc, 0, 0, 0);
      }
      const int rbase = rt * 16 + lg * 4;
      #pragma unroll
      for (int r = 0; r < 4; ++r) {
        int row = rbase + r;
        if (row < 100) {
          if (bcol < 100)      ob[1110 + row * 100 + bcol] = acc[r];
          else if (bcol < 110) ob[110 + row * 10 + (bcol - 100)] = acc[r];
        }
      }
    }
  }
}

extern "C" void kernel_launch(void* const* d_in, const int* in_sizes, int n_in,
                              void* d_out, int out_size, void* d_ws, size_t ws_size,
                              hipStream_t stream) {
  const float* x = (const float*)d_in[0];
  float* out = (float*)d_out;
  const int batch = in_sizes[0] / (C * L);   // 2048
  sig4_kernel<<<dim3(batch), dim3(256), 0, stream>>>(x, out);
}